// Round 6
// baseline (1792.378 us; speedup 1.0000x reference)
//
#include <hip/hip_runtime.h>
#include <hip/hip_bf16.h>
#include <math.h>

// SVD-compressed Llama block, MI355X/gfx950.  [R5: first execution crashed
// (core dump, no absmax). Top hypothesis: ws_size < the 375 MB layout ->
// OOB d_ws writes -> HSA abort. Fix: 240.4 MB layout (chunked attention S,
// chunked FFN INTER with fp32 td accumulation, h2 in d_out) + ws-size guard
// that writes a 1e30 sentinel instead of faulting, to make the failure mode
// diagnosable next round.]
// GEMM core unchanged (m97 structure: 128x128 tile, BK=32, 4 waves,
// mfma_f32_16x16x32_bf16, global_load_lds width-16, 2-barrier K-loop,
// bijective XCD tile swizzle).

typedef unsigned short u16;                                   // raw bf16 bits
typedef __bf16 bf16x8 __attribute__((ext_vector_type(8)));    // MFMA A/B frag
typedef float f32x4 __attribute__((ext_vector_type(4)));      // MFMA C/D frag

__device__ __forceinline__ u16 f2bf(float f) {                // RNE f32->bf16
  unsigned u = __float_as_uint(f);
  u += 0x7fffu + ((u >> 16) & 1u);
  return (u16)(u >> 16);
}
__device__ __forceinline__ float bf2f(u16 b) {
  return __uint_as_float(((unsigned)b) << 16);
}

#define BM 128
#define BN 128
#define BK 32

typedef __attribute__((address_space(1))) void gvoid;
typedef __attribute__((address_space(3))) void lvoid;

__device__ __forceinline__ void gl_lds16(const u16* g, u16* l) {
  // dest = wave-uniform LDS base + lane*16B; src is per-lane (guide §5).
  __builtin_amdgcn_global_load_lds((gvoid*)g, (lvoid*)l, 16, 0, 0);
}

// Generic batched NT-GEMM: C = alpha * A(M,K) x B(N,K)^T  (bf16 in, fp32 acc)
// Batch z: Aoff=(z/zdiv)*sAo+(z%zdiv)*sAi ; Boff=(z/zdiv)*sBo+((z%zdiv)/repB)*sBi
//          Coff=(z/zdiv)*sCo+(z%zdiv)*sCi   (GQA = repB)
// EPI 0: bf16 store. EPI 1: fp32 store of acc + Add[idx] (residual fuse).
// EPI 2: bf16 store of silu(acc) * Up[idx] (gate GEMM; Add carries up ptr).
// EPI 3: fp32 C += acc (K-split accumulate). EPI 4: fp32 C = acc (first split).
// causal: skip tiles with tn>tm (BM==BN). kcausal: K limited to (tm+1)*BM.
template<int EPI>
__global__ __launch_bounds__(256, 2)
void gemm_nt(const u16* __restrict__ A, const u16* __restrict__ B,
             void* __restrict__ Cv, const float* __restrict__ Add,
             int M, int N, int K, int lda, int ldb, int ldc,
             int zdiv, int repB,
             long sAo, long sAi, long sBo, long sBi, long sCo, long sCi,
             float alpha, int causal, int kcausal)
{
  // ---- bijective XCD-aware tile swizzle (m204): contiguous tile chunk per
  // XCD so neighbor tiles share operand panels in the XCD-private L2.
  int gx = gridDim.x, gy = gridDim.y;
  int nwg = gx * gy * gridDim.z;
  int orig = (blockIdx.z * gy + blockIdx.y) * gx + blockIdx.x;
  int q = nwg >> 3, r = nwg & 7;
  int xcd = orig & 7, i_in = orig >> 3;
  int id = (xcd < r ? xcd * (q + 1) : r * (q + 1) + (xcd - r) * q) + i_in;
  int tn = id % gx;
  int tm = (id / gx) % gy;
  int z = id / (gx * gy);

  if (causal && tn > tm) return;          // fully-masked causal tile
  A += (long)(z / zdiv) * sAo + (long)(z % zdiv) * sAi;
  B += (long)(z / zdiv) * sBo + (long)((z % zdiv) / repB) * sBi;
  long coff = (long)(z / zdiv) * sCo + (long)(z % zdiv) * sCi;

  int m0 = tm * BM, n0 = tn * BN;
  int Klim = kcausal ? min(K, (tm + 1) * BM) : K;

  __shared__ u16 As[BM * BK];             // [128][32] row-major, 8KB
  __shared__ u16 Bs[BN * BK];

  int tid = threadIdx.x;
  int lane = tid & 63, wave = tid >> 6;   // 4 waves, 2x2
  int wm = wave >> 1, wn = wave & 1;
  int srow = lane >> 2;                   // staging: 16 rows / 1KB chunk
  int kcol = (lane & 3) * 8;              // 8 bf16 = 16B per lane

  f32x4 acc[4][4];
  #pragma unroll
  for (int i = 0; i < 4; i++)
    #pragma unroll
    for (int j = 0; j < 4; j++)
      acc[i][j] = (f32x4){0.f, 0.f, 0.f, 0.f};

  int arow = wm * 64 + (lane & 15);       // A frag: row=lane&15, kbase=(lane>>4)*8
  int brow = wn * 64 + (lane & 15);       // B frag: col=lane&15 (NT layout)
  int kb = (lane >> 4) * 8;

  for (int k0 = 0; k0 < Klim; k0 += BK) {
    #pragma unroll
    for (int r2 = 0; r2 < 2; r2++) {      // 8KB per tile = 8 x 1KB chunks
      int chunk = wave + 4 * r2;          // wave-uniform chunk id
      int row = chunk * 16 + srow;
      gl_lds16(A + (long)(m0 + row) * lda + (k0 + kcol), &As[chunk * 512]);
      gl_lds16(B + (long)(n0 + row) * ldb + (k0 + kcol), &Bs[chunk * 512]);
    }
    __syncthreads();                      // compiler drains vmcnt before barrier
    bf16x8 af[4], bg[4];
    #pragma unroll
    for (int m = 0; m < 4; m++)
      af[m] = *reinterpret_cast<const bf16x8*>(&As[(arow + m * 16) * BK + kb]);
    #pragma unroll
    for (int n = 0; n < 4; n++)
      bg[n] = *reinterpret_cast<const bf16x8*>(&Bs[(brow + n * 16) * BK + kb]);
    #pragma unroll
    for (int m = 0; m < 4; m++)
      #pragma unroll
      for (int n = 0; n < 4; n++)
        acc[m][n] = __builtin_amdgcn_mfma_f32_16x16x32_bf16(af[m], bg[n], acc[m][n], 0, 0, 0);
    __syncthreads();                      // protect LDS before next stage
  }

  // C/D layout: col = lane&15, row = (lane>>4)*4 + j  (m89/m91-verified)
  int crow0 = m0 + wm * 64 + (lane >> 4) * 4;
  int ccol0 = n0 + wn * 64 + (lane & 15);
  if (EPI == 0) {
    u16* C = (u16*)Cv + coff;
    #pragma unroll
    for (int m = 0; m < 4; m++)
      #pragma unroll
      for (int n = 0; n < 4; n++)
        #pragma unroll
        for (int j = 0; j < 4; j++)
          C[(long)(crow0 + m * 16 + j) * ldc + (ccol0 + n * 16)] =
              f2bf(acc[m][n][j] * alpha);
  } else if (EPI == 1) {
    float* C = (float*)Cv + coff;
    const float* Ad = Add + coff;
    #pragma unroll
    for (int m = 0; m < 4; m++)
      #pragma unroll
      for (int n = 0; n < 4; n++)
        #pragma unroll
        for (int j = 0; j < 4; j++) {
          long idx = (long)(crow0 + m * 16 + j) * ldc + (ccol0 + n * 16);
          C[idx] = acc[m][n][j] * alpha + Ad[idx];
        }
  } else if (EPI == 2) {                  // ff = silu(acc) * up
    u16* C = (u16*)Cv + coff;
    const u16* U = (const u16*)Add;       // bf16 'up' buffer, same layout as C
    #pragma unroll
    for (int m = 0; m < 4; m++)
      #pragma unroll
      for (int n = 0; n < 4; n++)
        #pragma unroll
        for (int j = 0; j < 4; j++) {
          long idx = (long)(crow0 + m * 16 + j) * ldc + (ccol0 + n * 16);
          float g = acc[m][n][j] * alpha;
          C[idx] = f2bf(g / (1.f + __expf(-g)) * bf2f(U[idx]));
        }
  } else if (EPI == 3) {                  // fp32 C += acc (K-split accumulate)
    float* C = (float*)Cv + coff;
    #pragma unroll
    for (int m = 0; m < 4; m++)
      #pragma unroll
      for (int n = 0; n < 4; n++)
        #pragma unroll
        for (int j = 0; j < 4; j++) {
          long idx = (long)(crow0 + m * 16 + j) * ldc + (ccol0 + n * 16);
          C[idx] += acc[m][n][j];
        }
  } else {                                // EPI 4: fp32 C = acc (first split)
    float* C = (float*)Cv + coff;
    #pragma unroll
    for (int m = 0; m < 4; m++)
      #pragma unroll
      for (int n = 0; n < 4; n++)
        #pragma unroll
        for (int j = 0; j < 4; j++) {
          long idx = (long)(crow0 + m * 16 + j) * ldc + (ccol0 + n * 16);
          C[idx] = acc[m][n][j];
        }
  }
}

// ---- fp32 -> bf16 weight conversion, 14 tensors in one launch ----
struct ConvArgs {
  const float* src[14];
  u16* dst[14];
  int n4[14];                              // element count / 4
};
__global__ __launch_bounds__(256) void convert_all(ConvArgs a) {
  int seg = blockIdx.y;
  const float* s = a.src[seg];
  u16* d = a.dst[seg];
  int n4 = a.n4[seg];
  for (int i = blockIdx.x * 256 + threadIdx.x; i < n4; i += gridDim.x * 256) {
    float4 v = ((const float4*)s)[i];
    ushort4 o;
    o.x = f2bf(v.x); o.y = f2bf(v.y); o.z = f2bf(v.z); o.w = f2bf(v.w);
    ((ushort4*)d)[i] = o;
  }
}

// ---- single-tensor fp32 -> bf16 (td conversion) ----
__global__ __launch_bounds__(256)
void conv_f2b(const float* __restrict__ s, u16* __restrict__ d, int n4) {
  for (int i = blockIdx.x * 256 + threadIdx.x; i < n4; i += gridDim.x * 256) {
    float4 v = ((const float4*)s)[i];
    ushort4 o;
    o.x = f2bf(v.x); o.y = f2bf(v.y); o.z = f2bf(v.z); o.w = f2bf(v.w);
    ((ushort4*)d)[i] = o;
  }
}

// ---- ws-too-small sentinel: recognizable absmax, no fault ----
__global__ __launch_bounds__(256)
void sentinel_kernel(float* o, int n) {
  for (int i = blockIdx.x * 256 + threadIdx.x; i < n; i += gridDim.x * 256)
    o[i] = 1e30f;
}

// ---- RMSNorm row kernel: fp32 in -> bf16 out (D=4096, block=256) ----
__global__ __launch_bounds__(256)
void rmsnorm_kernel(const float* __restrict__ x, const float* __restrict__ w,
                    u16* __restrict__ out) {
  int row = blockIdx.x;
  const float4* xr = (const float4*)(x + (long)row * 4096);
  const float4* wr = (const float4*)w;
  int tid = threadIdx.x;
  float4 v[4];
  float ss = 0.f;
  #pragma unroll
  for (int i = 0; i < 4; i++) {
    v[i] = xr[tid + i * 256];
    ss += v[i].x * v[i].x + v[i].y * v[i].y + v[i].z * v[i].z + v[i].w * v[i].w;
  }
  #pragma unroll
  for (int off = 32; off; off >>= 1) ss += __shfl_down(ss, off);
  __shared__ float sm[4];
  if ((tid & 63) == 0) sm[tid >> 6] = ss;
  __syncthreads();
  float rs = rsqrtf((sm[0] + sm[1] + sm[2] + sm[3]) * (1.0f / 4096.0f) + 1e-5f);
  u16* orow = out + (long)row * 4096;
  #pragma unroll
  for (int i = 0; i < 4; i++) {
    float4 wv = wr[tid + i * 256];
    ushort4 o;
    o.x = f2bf(v[i].x * rs * wv.x);
    o.y = f2bf(v[i].y * rs * wv.y);
    o.z = f2bf(v[i].z * rs * wv.z);
    o.w = f2bf(v[i].w * rs * wv.w);
    ((ushort4*)orow)[tid + i * 256] = o;
  }
}

// ---- RoPE cos/sin table: tab[t*64+d] = (cos, sin)(t * invf[d]) ----
__global__ __launch_bounds__(256)
void rope_table_kernel(const float* __restrict__ invf, float2* __restrict__ tab) {
  int i = blockIdx.x * 256 + threadIdx.x;   // 65536 = 1024 x 64
  int t = i >> 6, d = i & 63;
  float ang = (float)t * invf[d];
  tab[i] = make_float2(cosf(ang), sinf(ang));
}

// ---- RoPE in-place on (rows=2048, Hloc*128) bf16, t = row & 1023 ----
__global__ __launch_bounds__(256)
void rope_kernel(u16* __restrict__ X, const float2* __restrict__ tab,
                 int Hloc, int ld) {
  int idx = blockIdx.x * 256 + threadIdx.x;  // one thread per (row,h,d) pair
  int ppr = Hloc * 64;
  int row = idx / ppr;
  int p = idx - row * ppr;
  int h = p >> 6, d = p & 63;
  int t = row & 1023;
  float2 cs = tab[(t << 6) | d];
  long base = (long)row * ld + h * 128 + d;
  float x1 = bf2f(X[base]), x2 = bf2f(X[base + 64]);
  X[base] = f2bf(x1 * cs.x - x2 * cs.y);
  X[base + 64] = f2bf(x2 * cs.x + x1 * cs.y);
}

// ---- V transpose: (b,t,hk,d) -> (b,hk,d,t)  bf16 ----
__global__ __launch_bounds__(256)
void vtrans_kernel(const u16* __restrict__ V, u16* __restrict__ Vt) {
  __shared__ u16 tile[32][33];
  int z = blockIdx.z;                      // b*8+hk
  int b = z >> 3, hk = z & 7;
  int t0 = blockIdx.x * 32, d0 = blockIdx.y * 32;
  int tx = threadIdx.x & 31, ty = threadIdx.x >> 5;  // 32x8
  #pragma unroll
  for (int i = 0; i < 32; i += 8) {
    int t = t0 + ty + i, d = d0 + tx;
    tile[ty + i][tx] = V[((long)(b * 1024 + t)) * 1024 + hk * 128 + d];
  }
  __syncthreads();
  #pragma unroll
  for (int i = 0; i < 32; i += 8) {
    int d = d0 + ty + i, t = t0 + tx;
    Vt[((long)((b * 8 + hk) * 128 + d)) * 1024 + t] = tile[tx][ty + i];
  }
}

// ---- causal softmax, wave per row, in-place on bf16 S (rows of 1024) ----
__global__ __launch_bounds__(256)
void softmax_kernel(u16* __restrict__ S) {
  int wv = threadIdx.x >> 6, lane = threadIdx.x & 63;
  long row = (long)blockIdx.x * 4 + wv;    // rows within this S chunk
  int t = (int)(row & 1023);
  int n = t + 1;                           // valid prefix length
  u16* r = S + row * 1024;
  float v[4][4];
  float m = -1e30f;
  #pragma unroll
  for (int i = 0; i < 4; i++) {
    int c = lane + i * 64;
    ushort4 u4 = ((const ushort4*)r)[c];
    int s0 = c * 4;
    v[i][0] = (s0 + 0 < n) ? bf2f(u4.x) : -1e30f;
    v[i][1] = (s0 + 1 < n) ? bf2f(u4.y) : -1e30f;
    v[i][2] = (s0 + 2 < n) ? bf2f(u4.z) : -1e30f;
    v[i][3] = (s0 + 3 < n) ? bf2f(u4.w) : -1e30f;
    m = fmaxf(m, fmaxf(fmaxf(v[i][0], v[i][1]), fmaxf(v[i][2], v[i][3])));
  }
  #pragma unroll
  for (int off = 32; off; off >>= 1) m = fmaxf(m, __shfl_xor(m, off));
  float sum = 0.f;
  #pragma unroll
  for (int i = 0; i < 4; i++)
    #pragma unroll
    for (int j = 0; j < 4; j++) {
      float e = __expf(v[i][j] - m);       // masked lanes -> exp(-huge) = 0
      v[i][j] = e;
      sum += e;
    }
  #pragma unroll
  for (int off = 32; off; off >>= 1) sum += __shfl_xor(sum, off);
  float inv = 1.f / sum;
  #pragma unroll
  for (int i = 0; i < 4; i++) {
    int c = lane + i * 64;
    ushort4 o;
    o.x = f2bf(v[i][0] * inv);
    o.y = f2bf(v[i][1] * inv);
    o.z = f2bf(v[i][2] * inv);
    o.w = f2bf(v[i][3] * inv);
    ((ushort4*)r)[c] = o;
  }
}

extern "C" void kernel_launch(void* const* d_in, const int* in_sizes, int n_in,
                              void* d_out, int out_size, void* d_ws, size_t ws_size,
                              hipStream_t stream) {
  // ---- workspace layout (bytes); total 240,386,048 ----
  static const long o_w_qUs = 0,         o_w_qV = 524288,     o_w_kUs = 17301504,
                    o_w_kV = 17432576,   o_w_vUs = 21626880,  o_w_vV = 21757952,
                    o_w_oUs = 25952256,  o_w_oV = 30146560,   o_w_gUs = 34340864,
                    o_w_gV = 63700992,   o_w_uUs = 72089600,  o_w_uV = 101449728,
                    o_w_dUs = 109838336, o_w_dV = 118226944,
                    o_h = 147587072,     o_xrq = 164364288,   o_xrk = 172752896,
                    o_xrv = 174850048,   o_Q = 176947200,     o_K = 193724416,
                    o_V = 197918720,     o_Vt = 202113024,    o_BIG = 206307328,
                    o_tab = 239861760;
  static const size_t NEED = 240386048;

  if (ws_size < NEED) {                   // diagnosable failure, not a fault
    sentinel_kernel<<<1024, 256, 0, stream>>>((float*)d_out, out_size);
    return;
  }

  const float* x    = (const float*)d_in[0];
  const float* ln1  = (const float*)d_in[1];
  const float* ln2  = (const float*)d_in[2];
  const float* invf = (const float*)d_in[17];
  char* ws = (char*)d_ws;

  u16* w_qUs = (u16*)(ws + o_w_qUs);
  u16* w_qV  = (u16*)(ws + o_w_qV);
  u16* w_kUs = (u16*)(ws + o_w_kUs);
  u16* w_kV  = (u16*)(ws + o_w_kV);
  u16* w_vUs = (u16*)(ws + o_w_vUs);
  u16* w_vV  = (u16*)(ws + o_w_vV);
  u16* w_oUs = (u16*)(ws + o_w_oUs);
  u16* w_oV  = (u16*)(ws + o_w_oV);
  u16* w_gUs = (u16*)(ws + o_w_gUs);
  u16* w_gV  = (u16*)(ws + o_w_gV);
  u16* w_uUs = (u16*)(ws + o_w_uUs);
  u16* w_uV  = (u16*)(ws + o_w_uV);
  u16* w_dUs = (u16*)(ws + o_w_dUs);
  u16* w_dV  = (u16*)(ws + o_w_dV);
  u16* hbf = (u16*)(ws + o_h);          // h / m bf16, 2048x4096
  u16* xrq = (u16*)(ws + o_xrq);        // 2048x2048
  u16* xrk = (u16*)(ws + o_xrk);        // 2048x512 (later t1)
  u16* xrv = (u16*)(ws + o_xrv);        // 2048x512
  u16* Qb  = (u16*)(ws + o_Q);          // (b,t,h,d); later attn out; later td
  u16* Kb  = (u16*)(ws + o_K);          // (b,t,hk,d) (later tg)
  u16* Vb  = (u16*)(ws + o_V);          // (b,t,hk,d) (later tu)
  u16* Vt  = (u16*)(ws + o_Vt);         // (b,hk,d,t)
  u16* Sch = (u16*)(ws + o_BIG);        // S chunk: 16 heads x 1024x1024 (32MB)
  u16* up_q = Sch;                      // FFN chunk: up (2048x3584) @ o_BIG
  u16* ff_q = Sch + 7340032;            // FFN chunk: ff (2048x3584)
  float* td = (float*)(ws + o_Q);       // fp32 2048x1024 (Qb dead by then)
  u16* tdb  = (u16*)(ws + o_Q + 8388608); // bf16 2048x1024
  float* h2 = (float*)d_out;            // residual lives in d_out
  float2* tab = (float2*)(ws + o_tab);  // RoPE table 1024x64
  u16* t1 = xrk;
  u16* tg = Kb;
  u16* tu = Vb;

  // 1) weights fp32 -> bf16 (d_in[3..16])
  ConvArgs ca;
  const int widx[14] = {3, 4, 5, 6, 7, 8, 9, 10, 11, 12, 13, 14, 15, 16};
  const long woff[14] = {o_w_qUs, o_w_qV, o_w_kUs, o_w_kV, o_w_vUs, o_w_vV,
                         o_w_oUs, o_w_oV, o_w_gUs, o_w_gV, o_w_uUs, o_w_uV,
                         o_w_dUs, o_w_dV};
  for (int i = 0; i < 14; i++) {
    ca.src[i] = (const float*)d_in[widx[i]];
    ca.dst[i] = (u16*)(ws + woff[i]);
    ca.n4[i] = in_sizes[widx[i]] / 4;
  }
  convert_all<<<dim3(2048, 14), 256, 0, stream>>>(ca);

  // 2) h = rmsnorm(x, ln1) -> bf16
  rmsnorm_kernel<<<2048, 256, 0, stream>>>(x, ln1, hbf);

  // 3) RoPE table
  rope_table_kernel<<<256, 256, 0, stream>>>(invf, tab);

  auto gemm0 = [&](const u16* A, const u16* B, u16* C,
                   int M, int N, int K, int lda, int ldb, int ldc,
                   int zb, int zdiv, int repB,
                   long sAo, long sAi, long sBo, long sBi, long sCo, long sCi,
                   float alpha, int causal, int kcausal) {
    dim3 g(N / BN, M / BM, zb);
    gemm_nt<0><<<g, 256, 0, stream>>>(A, B, (void*)C, nullptr, M, N, K,
                                      lda, ldb, ldc, zdiv, repB,
                                      sAo, sAi, sBo, sBi, sCo, sCi,
                                      alpha, causal, kcausal);
  };
  auto gemm1 = [&](const u16* A, const u16* B, float* C, const float* Ad,
                   int M, int N, int K, int lda, int ldb, int ldc) {
    dim3 g(N / BN, M / BM, 1);
    gemm_nt<1><<<g, 256, 0, stream>>>(A, B, (void*)C, Ad, M, N, K,
                                      lda, ldb, ldc, 1, 1,
                                      0, 0, 0, 0, 0, 0, 1.0f, 0, 0);
  };
  auto gemm2 = [&](const u16* A, const u16* B, u16* C, const u16* Up,
                   int M, int N, int K, int lda, int ldb, int ldc) {
    dim3 g(N / BN, M / BM, 1);
    gemm_nt<2><<<g, 256, 0, stream>>>(A, B, (void*)C, (const float*)Up,
                                      M, N, K, lda, ldb, ldc, 1, 1,
                                      0, 0, 0, 0, 0, 0, 1.0f, 0, 0);
  };
  auto gemmAcc = [&](const u16* A, const u16* B, float* C, int first,
                     int M, int N, int K, int lda, int ldb, int ldc) {
    dim3 g(N / BN, M / BM, 1);
    if (first)
      gemm_nt<4><<<g, 256, 0, stream>>>(A, B, (void*)C, nullptr, M, N, K,
                                        lda, ldb, ldc, 1, 1,
                                        0, 0, 0, 0, 0, 0, 1.0f, 0, 0);
    else
      gemm_nt<3><<<g, 256, 0, stream>>>(A, B, (void*)C, nullptr, M, N, K,
                                        lda, ldb, ldc, 1, 1,
                                        0, 0, 0, 0, 0, 0, 1.0f, 0, 0);
  };

  // 4) low-rank projections, stage 1: xr = h · V^T
  gemm0(hbf, w_qV, xrq, 2048, 2048, 4096, 4096, 4096, 2048, 1, 1, 1, 0, 0, 0, 0, 0, 0, 1.f, 0, 0);
  gemm0(hbf, w_kV, xrk, 2048, 512, 4096, 4096, 4096, 512, 1, 1, 1, 0, 0, 0, 0, 0, 0, 1.f, 0, 0);
  gemm0(hbf, w_vV, xrv, 2048, 512, 4096, 4096, 4096, 512, 1, 1, 1, 0, 0, 0, 0, 0, 0, 1.f, 0, 0);

  // 5) stage 2 per head: Q/K/V = xr_h · Us_h^T  (batched over heads)
  gemm0(xrq, w_qUs, Qb, 2048, 128, 64, 2048, 64, 4096, 32, 1, 1, 64, 0, 8192, 0, 128, 0, 1.f, 0, 0);
  gemm0(xrk, w_kUs, Kb, 2048, 128, 64, 512, 64, 1024, 8, 1, 1, 64, 0, 8192, 0, 128, 0, 1.f, 0, 0);
  gemm0(xrv, w_vUs, Vb, 2048, 128, 64, 512, 64, 1024, 8, 1, 1, 64, 0, 8192, 0, 128, 0, 1.f, 0, 0);

  // 6) RoPE on Q and K (in place)
  rope_kernel<<<16384, 256, 0, stream>>>(Qb, tab, 32, 4096);
  rope_kernel<<<4096, 256, 0, stream>>>(Kb, tab, 8, 1024);

  // 7) V^T for PV GEMM
  vtrans_kernel<<<dim3(32, 4, 16), 256, 0, stream>>>(Vb, Vt);

  // 8-10) attention in 4 chunks (batch x 16-head group); S chunk = 32 MB.
  // PV writes attn back into Qb's column range for those heads (Q data dead).
  const float scale = 0.08838834764831845f;
  for (int b = 0; b < 2; b++)
    for (int hg = 0; hg < 2; hg++) {
      const u16* Qbase = Qb + (long)b * 4194304 + hg * 2048;
      const u16* Kbase = Kb + (long)b * 1048576 + hg * 512;
      const u16* Vtb   = Vt + (long)b * 1048576 + hg * 524288;
      u16* AObase      = Qb + (long)b * 4194304 + hg * 2048;
      // S = scale · Q K^T   (z = head-in-group, GQA repB=4, causal tile-skip)
      gemm0(Qbase, Kbase, Sch, 1024, 1024, 128, 4096, 1024, 1024,
            16, 16, 4, 0, 128, 0, 128, 0, 1048576, scale, 1, 0);
      // causal softmax on 16 x 1024 rows
      softmax_kernel<<<4096, 256, 0, stream>>>(Sch);
      // attn = P · V  (kcausal limits K-loop to lower-triangular extent)
      gemm0(Sch, Vtb, AObase, 1024, 128, 1024, 1024, 1024, 4096,
            16, 16, 4, 0, 1048576, 0, 131072, 0, 128, 1.f, 0, 1);
    }

  // 11) O projection + residual: h2(=d_out) = x + (attn · oV^T) · oUs^T
  gemm0(Qb, w_oV, t1, 2048, 512, 4096, 4096, 4096, 512, 1, 1, 1, 0, 0, 0, 0, 0, 0, 1.f, 0, 0);
  gemm1(t1, w_oUs, h2, x, 2048, 4096, 512, 512, 512, 4096);

  // 12) m = rmsnorm(h2, ln2) -> bf16 (reuse hbf)
  rmsnorm_kernel<<<2048, 256, 0, stream>>>(h2, ln2, hbf);

  // 13) FFN stage 1: tu/tg (2048x1024)
  gemm0(hbf, w_uV, tu, 2048, 1024, 4096, 4096, 4096, 1024, 1, 1, 1, 0, 0, 0, 0, 0, 0, 1.f, 0, 0);
  gemm0(hbf, w_gV, tg, 2048, 1024, 4096, 4096, 4096, 1024, 1, 1, 1, 0, 0, 0, 0, 0, 0, 1.f, 0, 0);

  // 14) FFN INTER in 4 chunks of 3584: up -> ff=silu(gate)*up -> td += ff·dV^T
  for (int c = 0; c < 4; c++) {
    const u16* uUs_c = w_uUs + (long)c * 3584 * 1024;
    const u16* gUs_c = w_gUs + (long)c * 3584 * 1024;
    const u16* dV_c  = w_dV + (long)c * 3584;
    gemm0(tu, uUs_c, up_q, 2048, 3584, 1024, 1024, 1024, 3584, 1, 1, 1, 0, 0, 0, 0, 0, 0, 1.f, 0, 0);
    gemm2(tg, gUs_c, ff_q, up_q, 2048, 3584, 1024, 1024, 1024, 3584);
    gemmAcc(ff_q, dV_c, td, c == 0, 2048, 1024, 3584, 3584, 14336, 1024);
  }

  // 15) td -> bf16; out = h2 + td · dUs^T  (reads and rewrites d_out in place)
  conv_f2b<<<512, 256, 0, stream>>>(td, tdb, 524288);
  gemm1(tdb, w_dUs, (float*)d_out, (const float*)d_out, 2048, 4096, 1024, 1024, 1024, 4096);
}

// Round 10
// 1358.327 us; speedup vs baseline: 1.3195x; 1.3195x over previous
//
#include <hip/hip_runtime.h>
#include <hip/hip_bf16.h>
#include <math.h>

// SVD-compressed Llama block, MI355X/gfx950.  [R9: identical to R6/R7/R8 —
// three straight acquisition timeouts; this candidate has never run. R6 plan:
// K-split + fp32 atomicAdd accumulation (EPI5) and z-merged launches to fill
// the machine (R6 baseline 1792us was death-by-small-grids); balanced
// convert_all; TAG template for per-site profile names. GEMM staging/sync
// structure unchanged (m97, race-screened by R5's pass).]

typedef unsigned short u16;                                   // raw bf16 bits
typedef __bf16 bf16x8 __attribute__((ext_vector_type(8)));    // MFMA A/B frag
typedef float f32x4 __attribute__((ext_vector_type(4)));      // MFMA C/D frag

__device__ __forceinline__ u16 f2bf(float f) {                // RNE f32->bf16
  unsigned u = __float_as_uint(f);
  u += 0x7fffu + ((u >> 16) & 1u);
  return (u16)(u >> 16);
}
__device__ __forceinline__ float bf2f(u16 b) {
  return __uint_as_float(((unsigned)b) << 16);
}

#define BM 128
#define BN 128
#define BK 32

typedef __attribute__((address_space(1))) void gvoid;
typedef __attribute__((address_space(3))) void lvoid;

__device__ __forceinline__ void gl_lds16(const u16* g, u16* l) {
  __builtin_amdgcn_global_load_lds((gvoid*)g, (lvoid*)l, 16, 0, 0);
}

// Generic batched NT-GEMM: C = alpha * A(M,K) x B(N,K)^T  (bf16 in, fp32 acc)
// Batch z: Aoff=(z/zdiv)*sAo+(z%zdiv)*sAi ; Boff=(z/zdiv)*sBo+((z%zdiv)/repB)*sBi
//          Coff=(z/zdiv)*sCo+(z%zdiv)*sCi
// K-split usage: z%zdiv = split index s; sAi=sBi=Ksplit (column shift), sCi=0,
//                EPI=5 (atomicAdd into zeroed fp32 C).
// EPI 0: bf16 store. 1: fp32 acc+Add. 2: bf16 silu(acc)*Up. 5: fp32 atomicAdd.
// TAG: distinguishes call sites in rocprof kernel names only.
template<int EPI, int TAG>
__global__ __launch_bounds__(256, 2)
void gemm_nt(const u16* __restrict__ A, const u16* __restrict__ B,
             void* __restrict__ Cv, const float* __restrict__ Add,
             int M, int N, int K, int lda, int ldb, int ldc,
             int zdiv, int repB,
             long sAo, long sAi, long sBo, long sBi, long sCo, long sCi,
             float alpha, int causal, int kcausal)
{
  // bijective XCD-aware tile swizzle (m204)
  int gx = gridDim.x, gy = gridDim.y;
  int nwg = gx * gy * gridDim.z;
  int orig = (blockIdx.z * gy + blockIdx.y) * gx + blockIdx.x;
  int q = nwg >> 3, r = nwg & 7;
  int xcd = orig & 7, i_in = orig >> 3;
  int id = (xcd < r ? xcd * (q + 1) : r * (q + 1) + (xcd - r) * q) + i_in;
  int tn = id % gx;
  int tm = (id / gx) % gy;
  int z = id / (gx * gy);

  if (causal && tn > tm) return;          // fully-masked causal tile
  A += (long)(z / zdiv) * sAo + (long)(z % zdiv) * sAi;
  B += (long)(z / zdiv) * sBo + (long)((z % zdiv) / repB) * sBi;
  long coff = (long)(z / zdiv) * sCo + (long)(z % zdiv) * sCi;

  int m0 = tm * BM, n0 = tn * BN;
  int Klim = kcausal ? min(K, (tm + 1) * BM) : K;

  __shared__ u16 As[BM * BK];             // [128][32] row-major, 8KB
  __shared__ u16 Bs[BN * BK];

  int tid = threadIdx.x;
  int lane = tid & 63, wave = tid >> 6;   // 4 waves, 2x2
  int wm = wave >> 1, wn = wave & 1;
  int srow = lane >> 2;                   // staging: 16 rows / 1KB chunk
  int kcol = (lane & 3) * 8;              // 8 bf16 = 16B per lane

  f32x4 acc[4][4];
  #pragma unroll
  for (int i = 0; i < 4; i++)
    #pragma unroll
    for (int j = 0; j < 4; j++)
      acc[i][j] = (f32x4){0.f, 0.f, 0.f, 0.f};

  int arow = wm * 64 + (lane & 15);
  int brow = wn * 64 + (lane & 15);
  int kb = (lane >> 4) * 8;

  for (int k0 = 0; k0 < Klim; k0 += BK) {
    #pragma unroll
    for (int r2 = 0; r2 < 2; r2++) {      // 8KB per tile = 8 x 1KB chunks
      int chunk = wave + 4 * r2;
      int row = chunk * 16 + srow;
      gl_lds16(A + (long)(m0 + row) * lda + (k0 + kcol), &As[chunk * 512]);
      gl_lds16(B + (long)(n0 + row) * ldb + (k0 + kcol), &Bs[chunk * 512]);
    }
    __syncthreads();
    bf16x8 af[4], bg[4];
    #pragma unroll
    for (int m = 0; m < 4; m++)
      af[m] = *reinterpret_cast<const bf16x8*>(&As[(arow + m * 16) * BK + kb]);
    #pragma unroll
    for (int n = 0; n < 4; n++)
      bg[n] = *reinterpret_cast<const bf16x8*>(&Bs[(brow + n * 16) * BK + kb]);
    #pragma unroll
    for (int m = 0; m < 4; m++)
      #pragma unroll
      for (int n = 0; n < 4; n++)
        acc[m][n] = __builtin_amdgcn_mfma_f32_16x16x32_bf16(af[m], bg[n], acc[m][n], 0, 0, 0);
    __syncthreads();
  }

  // C/D layout: col = lane&15, row = (lane>>4)*4 + j  (m89/m91-verified)
  int crow0 = m0 + wm * 64 + (lane >> 4) * 4;
  int ccol0 = n0 + wn * 64 + (lane & 15);
  if (EPI == 0) {
    u16* C = (u16*)Cv + coff;
    #pragma unroll
    for (int m = 0; m < 4; m++)
      #pragma unroll
      for (int n = 0; n < 4; n++)
        #pragma unroll
        for (int j = 0; j < 4; j++)
          C[(long)(crow0 + m * 16 + j) * ldc + (ccol0 + n * 16)] =
              f2bf(acc[m][n][j] * alpha);
  } else if (EPI == 1) {
    float* C = (float*)Cv + coff;
    const float* Ad = Add + coff;
    #pragma unroll
    for (int m = 0; m < 4; m++)
      #pragma unroll
      for (int n = 0; n < 4; n++)
        #pragma unroll
        for (int j = 0; j < 4; j++) {
          long idx = (long)(crow0 + m * 16 + j) * ldc + (ccol0 + n * 16);
          C[idx] = acc[m][n][j] * alpha + Ad[idx];
        }
  } else if (EPI == 2) {                  // ff = silu(acc) * up
    u16* C = (u16*)Cv + coff;
    const u16* U = (const u16*)Add;
    #pragma unroll
    for (int m = 0; m < 4; m++)
      #pragma unroll
      for (int n = 0; n < 4; n++)
        #pragma unroll
        for (int j = 0; j < 4; j++) {
          long idx = (long)(crow0 + m * 16 + j) * ldc + (ccol0 + n * 16);
          float g = acc[m][n][j] * alpha;
          C[idx] = f2bf(g / (1.f + __expf(-g)) * bf2f(U[idx]));
        }
  } else {                                // EPI 5: fp32 atomicAdd (K-split)
    float* C = (float*)Cv + coff;
    #pragma unroll
    for (int m = 0; m < 4; m++)
      #pragma unroll
      for (int n = 0; n < 4; n++)
        #pragma unroll
        for (int j = 0; j < 4; j++) {
          long idx = (long)(crow0 + m * 16 + j) * ldc + (ccol0 + n * 16);
          atomicAdd(&C[idx], acc[m][n][j] * alpha);
        }
  }
}

template<int EPI, int TAG>
static void launch_gemm(dim3 g, hipStream_t s,
                        const u16* A, const u16* B, void* C, const void* Add,
                        int M, int N, int K, int lda, int ldb, int ldc,
                        int zdiv, int repB,
                        long sAo, long sAi, long sBo, long sBi, long sCo, long sCi,
                        float alpha, int causal, int kcausal) {
  gemm_nt<EPI, TAG><<<g, 256, 0, s>>>(A, B, C, (const float*)Add, M, N, K,
                                      lda, ldb, ldc, zdiv, repB,
                                      sAo, sAi, sBo, sBi, sCo, sCi,
                                      alpha, causal, kcausal);
}

// ---- fp32 -> bf16 weight conversion, 14 tensors, load-balanced ----
struct ConvArgs {
  const float* src[14];
  u16* dst[14];
  int cum[15];                             // cumulative n4 (exclusive prefix)
};
__global__ __launch_bounds__(256) void convert_all(ConvArgs a) {
  int total = a.cum[14];
  for (int g = blockIdx.x * 256 + threadIdx.x; g < total; g += gridDim.x * 256) {
    int seg = 0;
    #pragma unroll
    for (int s = 1; s < 14; s++) seg += (g >= a.cum[s]);
    int i = g - a.cum[seg];
    float4 v = ((const float4*)a.src[seg])[i];
    ushort4 o;
    o.x = f2bf(v.x); o.y = f2bf(v.y); o.z = f2bf(v.z); o.w = f2bf(v.w);
    ((ushort4*)a.dst[seg])[i] = o;
  }
}

// ---- single-tensor fp32 -> bf16 ----
__global__ __launch_bounds__(256)
void conv_f2b(const float* __restrict__ s, u16* __restrict__ d, int n4) {
  for (int i = blockIdx.x * 256 + threadIdx.x; i < n4; i += gridDim.x * 256) {
    float4 v = ((const float4*)s)[i];
    ushort4 o;
    o.x = f2bf(v.x); o.y = f2bf(v.y); o.z = f2bf(v.z); o.w = f2bf(v.w);
    ((ushort4*)d)[i] = o;
  }
}

// ---- zero fp32 region (for atomic accumulators) ----
__global__ __launch_bounds__(256)
void zero_kernel(float4* p, int n4) {
  for (int i = blockIdx.x * 256 + threadIdx.x; i < n4; i += gridDim.x * 256)
    p[i] = (float4){0.f, 0.f, 0.f, 0.f};
}

// ---- ws-too-small sentinel ----
__global__ __launch_bounds__(256)
void sentinel_kernel(float* o, int n) {
  for (int i = blockIdx.x * 256 + threadIdx.x; i < n; i += gridDim.x * 256)
    o[i] = 1e30f;
}

// ---- RMSNorm row kernel: fp32 in -> bf16 out (D=4096, block=256) ----
__global__ __launch_bounds__(256)
void rmsnorm_kernel(const float* __restrict__ x, const float* __restrict__ w,
                    u16* __restrict__ out) {
  int row = blockIdx.x;
  const float4* xr = (const float4*)(x + (long)row * 4096);
  const float4* wr = (const float4*)w;
  int tid = threadIdx.x;
  float4 v[4];
  float ss = 0.f;
  #pragma unroll
  for (int i = 0; i < 4; i++) {
    v[i] = xr[tid + i * 256];
    ss += v[i].x * v[i].x + v[i].y * v[i].y + v[i].z * v[i].z + v[i].w * v[i].w;
  }
  #pragma unroll
  for (int off = 32; off; off >>= 1) ss += __shfl_down(ss, off);
  __shared__ float sm[4];
  if ((tid & 63) == 0) sm[tid >> 6] = ss;
  __syncthreads();
  float rs = rsqrtf((sm[0] + sm[1] + sm[2] + sm[3]) * (1.0f / 4096.0f) + 1e-5f);
  u16* orow = out + (long)row * 4096;
  #pragma unroll
  for (int i = 0; i < 4; i++) {
    float4 wv = wr[tid + i * 256];
    ushort4 o;
    o.x = f2bf(v[i].x * rs * wv.x);
    o.y = f2bf(v[i].y * rs * wv.y);
    o.z = f2bf(v[i].z * rs * wv.z);
    o.w = f2bf(v[i].w * rs * wv.w);
    ((ushort4*)orow)[tid + i * 256] = o;
  }
}

// ---- RoPE cos/sin table ----
__global__ __launch_bounds__(256)
void rope_table_kernel(const float* __restrict__ invf, float2* __restrict__ tab) {
  int i = blockIdx.x * 256 + threadIdx.x;   // 65536 = 1024 x 64
  int t = i >> 6, d = i & 63;
  float ang = (float)t * invf[d];
  tab[i] = make_float2(cosf(ang), sinf(ang));
}

// ---- RoPE in-place ----
__global__ __launch_bounds__(256)
void rope_kernel(u16* __restrict__ X, const float2* __restrict__ tab,
                 int Hloc, int ld) {
  int idx = blockIdx.x * 256 + threadIdx.x;
  int ppr = Hloc * 64;
  int row = idx / ppr;
  int p = idx - row * ppr;
  int h = p >> 6, d = p & 63;
  int t = row & 1023;
  float2 cs = tab[(t << 6) | d];
  long base = (long)row * ld + h * 128 + d;
  float x1 = bf2f(X[base]), x2 = bf2f(X[base + 64]);
  X[base] = f2bf(x1 * cs.x - x2 * cs.y);
  X[base + 64] = f2bf(x2 * cs.x + x1 * cs.y);
}

// ---- V transpose: (b,t,hk,d) -> (b,hk,d,t) ----
__global__ __launch_bounds__(256)
void vtrans_kernel(const u16* __restrict__ V, u16* __restrict__ Vt) {
  __shared__ u16 tile[32][33];
  int z = blockIdx.z;
  int b = z >> 3, hk = z & 7;
  int t0 = blockIdx.x * 32, d0 = blockIdx.y * 32;
  int tx = threadIdx.x & 31, ty = threadIdx.x >> 5;
  #pragma unroll
  for (int i = 0; i < 32; i += 8) {
    int t = t0 + ty + i, d = d0 + tx;
    tile[ty + i][tx] = V[((long)(b * 1024 + t)) * 1024 + hk * 128 + d];
  }
  __syncthreads();
  #pragma unroll
  for (int i = 0; i < 32; i += 8) {
    int d = d0 + ty + i, t = t0 + tx;
    Vt[((long)((b * 8 + hk) * 128 + d)) * 1024 + t] = tile[tx][ty + i];
  }
}

// ---- causal softmax, wave per row, in-place on bf16 S (rows of 1024) ----
__global__ __launch_bounds__(256)
void softmax_kernel(u16* __restrict__ S) {
  int wv = threadIdx.x >> 6, lane = threadIdx.x & 63;
  long row = (long)blockIdx.x * 4 + wv;
  int t = (int)(row & 1023);
  int n = t + 1;
  u16* r = S + row * 1024;
  float v[4][4];
  float m = -1e30f;
  #pragma unroll
  for (int i = 0; i < 4; i++) {
    int c = lane + i * 64;
    ushort4 u4 = ((const ushort4*)r)[c];
    int s0 = c * 4;
    v[i][0] = (s0 + 0 < n) ? bf2f(u4.x) : -1e30f;
    v[i][1] = (s0 + 1 < n) ? bf2f(u4.y) : -1e30f;
    v[i][2] = (s0 + 2 < n) ? bf2f(u4.z) : -1e30f;
    v[i][3] = (s0 + 3 < n) ? bf2f(u4.w) : -1e30f;
    m = fmaxf(m, fmaxf(fmaxf(v[i][0], v[i][1]), fmaxf(v[i][2], v[i][3])));
  }
  #pragma unroll
  for (int off = 32; off; off >>= 1) m = fmaxf(m, __shfl_xor(m, off));
  float sum = 0.f;
  #pragma unroll
  for (int i = 0; i < 4; i++)
    #pragma unroll
    for (int j = 0; j < 4; j++) {
      float e = __expf(v[i][j] - m);
      v[i][j] = e;
      sum += e;
    }
  #pragma unroll
  for (int off = 32; off; off >>= 1) sum += __shfl_xor(sum, off);
  float inv = 1.f / sum;
  #pragma unroll
  for (int i = 0; i < 4; i++) {
    int c = lane + i * 64;
    ushort4 o;
    o.x = f2bf(v[i][0] * inv);
    o.y = f2bf(v[i][1] * inv);
    o.z = f2bf(v[i][2] * inv);
    o.w = f2bf(v[i][3] * inv);
    ((ushort4*)r)[c] = o;
  }
}

extern "C" void kernel_launch(void* const* d_in, const int* in_sizes, int n_in,
                              void* d_out, int out_size, void* d_ws, size_t ws_size,
                              hipStream_t stream) {
  // ---- workspace layout (bytes); total 240,386,048 (passed on R5) ----
  static const long o_w_qUs = 0,         o_w_qV = 524288,     o_w_kUs = 17301504,
                    o_w_kV = 17432576,   o_w_vUs = 21626880,  o_w_vV = 21757952,
                    o_w_oUs = 25952256,  o_w_oV = 30146560,   o_w_gUs = 34340864,
                    o_w_gV = 63700992,   o_w_uUs = 72089600,  o_w_uV = 101449728,
                    o_w_dUs = 109838336, o_w_dV = 118226944,
                    o_h = 147587072,     o_xrq = 164364288,   o_xrk = 172752896,
                    o_xrv = 174850048,   o_Q = 176947200,     o_K = 193724416,
                    o_V = 197918720,     o_Vt = 202113024,    o_BIG = 206307328,
                    o_tab = 239861760;
  static const size_t NEED = 240386048;

  if (ws_size < NEED) {
    sentinel_kernel<<<1024, 256, 0, stream>>>((float*)d_out, out_size);
    return;
  }

  const float* x    = (const float*)d_in[0];
  const float* ln1  = (const float*)d_in[1];
  const float* ln2  = (const float*)d_in[2];
  const float* invf = (const float*)d_in[17];
  char* ws = (char*)d_ws;

  u16* w_qUs = (u16*)(ws + o_w_qUs);
  u16* w_qV  = (u16*)(ws + o_w_qV);
  u16* w_kUs = (u16*)(ws + o_w_kUs);
  u16* w_kV  = (u16*)(ws + o_w_kV);
  u16* w_oUs = (u16*)(ws + o_w_oUs);
  u16* w_oV  = (u16*)(ws + o_w_oV);
  u16* w_gUs = (u16*)(ws + o_w_gUs);
  u16* w_gV  = (u16*)(ws + o_w_gV);
  u16* w_uUs = (u16*)(ws + o_w_uUs);
  u16* w_dUs = (u16*)(ws + o_w_dUs);
  u16* w_dV  = (u16*)(ws + o_w_dV);
  u16* hbf = (u16*)(ws + o_h);          // h / m bf16, 2048x4096
  u16* xrq = (u16*)(ws + o_xrq);        // 2048x2048 (then t1-free zone)
  u16* xrk = (u16*)(ws + o_xrk);        // 2048x512 (later t1)
  u16* Qb  = (u16*)(ws + o_Q);          // Q/attn; later td+tdb
  u16* Kb  = (u16*)(ws + o_K);          // K (later tg)
  u16* Vb  = (u16*)(ws + o_V);          // V (later tu)
  u16* Vt  = (u16*)(ws + o_Vt);
  u16* Sch = (u16*)(ws + o_BIG);        // attention S chunk (32MB)
  float* bigf = (float*)(ws + o_BIG);   // fp32 atomic accumulators (aliased)
  u16* up_q = Sch;                      // FFN chunk: up (2048x3584)
  u16* ff_q = Sch + 7340032;            // FFN chunk: ff
  float* td = (float*)(ws + o_Q);       // fp32 2048x1024 (Qb dead by then)
  u16* tdb  = (u16*)(ws + o_Q + 8388608);
  float* h2 = (float*)d_out;
  float2* tab = (float2*)(ws + o_tab);
  u16* t1 = xrk;
  u16* tg = Kb;
  u16* tu = Vb;

  // 1) weights fp32 -> bf16, load-balanced over global index
  ConvArgs ca;
  const int widx[14] = {3, 4, 5, 6, 7, 8, 9, 10, 11, 12, 13, 14, 15, 16};
  const long woff[14] = {o_w_qUs, o_w_qV, o_w_kUs, o_w_kV, o_w_vUs, o_w_vV,
                         o_w_oUs, o_w_oV, o_w_gUs, o_w_gV, o_w_uUs, o_w_uV,
                         o_w_dUs, o_w_dV};
  int cum = 0;
  for (int i = 0; i < 14; i++) {
    ca.src[i] = (const float*)d_in[widx[i]];
    ca.dst[i] = (u16*)(ws + woff[i]);
    ca.cum[i] = cum;
    cum += in_sizes[widx[i]] / 4;
  }
  ca.cum[14] = cum;                       // 18,448,384 float4s total
  convert_all<<<2048, 256, 0, stream>>>(ca);

  // 2) h = rmsnorm(x, ln1); 3) RoPE table
  rmsnorm_kernel<<<2048, 256, 0, stream>>>(x, ln1, hbf);
  rope_table_kernel<<<256, 256, 0, stream>>>(invf, tab);

  // 4) stage 1 xr GEMMs, K-split into fp32 atomic accumulators in BIG:
  //    layout: [xrq_f32: 4,194,304 fl][xrk_f32: 1,048,576][xrv_f32: 1,048,576]
  float* xrq_f32  = bigf;
  float* xrkv_f32 = bigf + 4194304;
  zero_kernel<<<1024, 256, 0, stream>>>((float4*)bigf, 1572864);
  // xrq: z=2 K-splits of 2048 -> grid 16x16x2 = 512 blocks
  launch_gemm<5, 0>(dim3(16, 16, 2), stream, hbf, w_qV, xrq_f32, nullptr,
                    2048, 2048, 2048, 4096, 4096, 2048,
                    2, 1, 0, 2048, 0, 2048, 0, 0, 1.f, 0, 0);
  // xrk+xrv merged (z/4 = tensor, z%4 = K-split of 1024) -> 4x16x8 = 512
  launch_gemm<5, 1>(dim3(4, 16, 8), stream, hbf, w_kV, xrkv_f32, nullptr,
                    2048, 512, 1024, 4096, 4096, 512,
                    4, 1, 0, 1024, 2162688, 1024, 1048576, 0, 1.f, 0, 0);
  // convert all three (contiguous src in BIG, contiguous dst xrq|xrk|xrv)
  conv_f2b<<<2048, 256, 0, stream>>>(bigf, xrq, 1572864);

  // 5) stage 2: Q (z=32 heads); K+V merged (z/8 = tensor, z%8 = head)
  launch_gemm<0, 2>(dim3(1, 16, 32), stream, xrq, w_qUs, Qb, nullptr,
                    2048, 128, 64, 2048, 64, 4096,
                    1, 1, 64, 0, 8192, 0, 128, 0, 1.f, 0, 0);
  launch_gemm<0, 3>(dim3(1, 16, 16), stream, xrk, w_kUs, Kb, nullptr,
                    2048, 128, 64, 512, 64, 1024,
                    8, 1, 1048576, 64, 2162688, 8192, 2097152, 128, 1.f, 0, 0);

  // 6) RoPE; 7) V^T
  rope_kernel<<<16384, 256, 0, stream>>>(Qb, tab, 32, 4096);
  rope_kernel<<<4096, 256, 0, stream>>>(Kb, tab, 8, 1024);
  vtrans_kernel<<<dim3(32, 4, 16), 256, 0, stream>>>(Vb, Vt);

  // 8-10) attention in 4 chunks (b x 16-head group); S chunk 32 MB in BIG
  const float scale = 0.08838834764831845f;
  for (int b = 0; b < 2; b++)
    for (int hg = 0; hg < 2; hg++) {
      const u16* Qbase = Qb + (long)b * 4194304 + hg * 2048;
      const u16* Kbase = Kb + (long)b * 1048576 + hg * 512;
      const u16* Vtb   = Vt + (long)b * 1048576 + hg * 524288;
      u16* AObase      = Qb + (long)b * 4194304 + hg * 2048;
      launch_gemm<0, 4>(dim3(8, 8, 16), stream, Qbase, Kbase, Sch, nullptr,
                        1024, 1024, 128, 4096, 1024, 1024,
                        16, 4, 0, 128, 0, 128, 0, 1048576, scale, 1, 0);
      softmax_kernel<<<4096, 256, 0, stream>>>(Sch);
      launch_gemm<0, 5>(dim3(1, 8, 16), stream, Sch, Vtb, AObase, nullptr,
                        1024, 128, 1024, 1024, 1024, 4096,
                        16, 4, 0, 1048576, 0, 131072, 0, 128, 1.f, 0, 1);
    }

  // 11) O projection: t1 via K-split atomic (BIG free again), then residual
  float* t1_f32 = bigf;
  zero_kernel<<<1024, 256, 0, stream>>>((float4*)t1_f32, 262144);
  launch_gemm<5, 6>(dim3(4, 16, 4), stream, Qb, w_oV, t1_f32, nullptr,
                    2048, 512, 1024, 4096, 4096, 512,
                    4, 1, 0, 1024, 0, 1024, 0, 0, 1.f, 0, 0);
  conv_f2b<<<1024, 256, 0, stream>>>(t1_f32, t1, 262144);
  launch_gemm<1, 7>(dim3(32, 16, 1), stream, t1, w_oUs, h2, x,
                    2048, 4096, 512, 512, 512, 4096,
                    1, 1, 0, 0, 0, 0, 0, 0, 1.f, 0, 0);

  // 12) m = rmsnorm(h2, ln2)
  rmsnorm_kernel<<<2048, 256, 0, stream>>>(h2, ln2, hbf);

  // 13) FFN stage 1: gV+uV merged K-split atomic -> tg_f32|tu_f32 in BIG
  float* tg_f32 = bigf;
  zero_kernel<<<1024, 256, 0, stream>>>((float4*)tg_f32, 1048576);
  launch_gemm<5, 8>(dim3(8, 16, 8), stream, hbf, w_gV, tg_f32, nullptr,
                    2048, 1024, 1024, 4096, 4096, 1024,
                    4, 1, 0, 1024, 18874368, 1024, 2097152, 0, 1.f, 0, 0);
  conv_f2b<<<2048, 256, 0, stream>>>(tg_f32, tg, 1048576);  // -> tg(Kb)|tu(Vb)

  // 14) FFN INTER in 4 chunks of 3584; dV accumulation K-split atomic into td
  zero_kernel<<<1024, 256, 0, stream>>>((float4*)td, 524288);
  for (int c = 0; c < 4; c++) {
    const u16* uUs_c = w_uUs + (long)c * 3584 * 1024;
    const u16* gUs_c = w_gUs + (long)c * 3584 * 1024;
    const u16* dV_c  = w_dV + (long)c * 3584;
    launch_gemm<0, 9>(dim3(28, 16, 1), stream, tu, uUs_c, up_q, nullptr,
                      2048, 3584, 1024, 1024, 1024, 3584,
                      1, 1, 0, 0, 0, 0, 0, 0, 1.f, 0, 0);
    launch_gemm<2, 10>(dim3(28, 16, 1), stream, tg, gUs_c, ff_q, up_q,
                       2048, 3584, 1024, 1024, 1024, 3584,
                       1, 1, 0, 0, 0, 0, 0, 0, 1.f, 0, 0);
    launch_gemm<5, 11>(dim3(8, 16, 4), stream, ff_q, dV_c, td, nullptr,
                       2048, 1024, 896, 3584, 14336, 1024,
                       4, 1, 0, 896, 0, 896, 0, 0, 1.f, 0, 0);
  }

  // 15) td -> bf16; out = h2 + td · dUs^T (in-place read/write of d_out)
  conv_f2b<<<1024, 256, 0, stream>>>(td, tdb, 524288);
  launch_gemm<1, 12>(dim3(32, 16, 1), stream, tdb, w_dUs, (float*)d_out,
                     (const float*)d_out, 2048, 4096, 1024, 1024, 1024, 4096,
                     1, 1, 0, 0, 0, 0, 0, 0, 1.f, 0, 0);
}